// Round 9
// baseline (838.034 us; speedup 1.0000x reference)
//
#include <hip/hip_runtime.h>
#include <hip/hip_bf16.h>

typedef __hip_bfloat16 bf16;
typedef __attribute__((ext_vector_type(8))) short short8;
typedef __attribute__((ext_vector_type(4))) float f32x4;

#define HDIM 512
#define SLOPE 0.01f
#define BN_EPS 1e-5f

__device__ inline float bf2f(short s) {
    unsigned u = ((unsigned)(unsigned short)s) << 16;
    return __builtin_bit_cast(float, u);
}
__device__ inline unsigned short f2bfbits(float v) {
    bf16 h = __float2bfloat16(v);
    return (unsigned short)__builtin_bit_cast(short, h);
}

// ---------------- runtime dtype detection ----------------
// flags[0]=1 if indices int64; flags[1]=1 if float tensors fp32.
__global__ void detect_types(const int* __restrict__ ei, const unsigned* __restrict__ xw,
                             int* __restrict__ flags) {
    __shared__ int nzhi, okbf;
    if (threadIdx.x == 0) { nzhi = 0; okbf = 0; }
    __syncthreads();
    int lo = 0, ok = 0;
    for (int i = threadIdx.x; i < 2048; i += 256)
        if (ei[2 * i + 1] != 0) lo++;
    for (int i = threadIdx.x; i < 1024; i += 256) {
        unsigned w = (xw[i] & 0xFFFFu) << 16;
        float av = fabsf(__builtin_bit_cast(float, w));
        if (av > 0.0009f && av < 64.0f) ok++;
    }
    if (lo) atomicAdd(&nzhi, lo);
    if (ok) atomicAdd(&okbf, ok);
    __syncthreads();
    if (threadIdx.x == 0) {
        flags[0] = (nzhi == 0) ? 1 : 0;
        flags[1] = (okbf < 512) ? 1 : 0;
    }
}

__global__ void conv_idx(const int* __restrict__ src, int* __restrict__ dst, int n,
                         const int* __restrict__ flags) {
    int i = blockIdx.x * blockDim.x + threadIdx.x;
    if (i < n) dst[i] = flags[0] ? (int)((const long long*)src)[i] : src[i];
}

__global__ void conv_float(const void* __restrict__ src, bf16* __restrict__ dst, int n,
                           const int* __restrict__ flags) {
    int i = blockIdx.x * blockDim.x + threadIdx.x;
    if (i < n)
        dst[i] = flags[1] ? __float2bfloat16(((const float*)src)[i])
                          : ((const bf16*)src)[i];
}

// transpose + convert weight: WT[nn][k] = W[k][nn]  (W is [K][Nn])
__global__ void wt_conv(const void* __restrict__ W, bf16* __restrict__ WT,
                        int K, int Nn, const int* __restrict__ flags) {
    int idx = blockIdx.x * 256 + threadIdx.x;
    if (idx >= K * Nn) return;
    int nn = idx / K;
    int k = idx - nn * K;
    float v = flags[1] ? ((const float*)W)[(size_t)k * Nn + nn]
                       : __bfloat162float(((const bf16*)W)[(size_t)k * Nn + nn]);
    WT[idx] = __float2bfloat16(v);
}

// ---------------- degree + CSR build ----------------
__global__ void count_deg(const int* __restrict__ col, int* __restrict__ cnt, int e) {
    int i = blockIdx.x * blockDim.x + threadIdx.x;
    if (i < e) atomicAdd(&cnt[col[i]], 1);
}

__global__ void finalize_deg(const int* __restrict__ cnt, float* __restrict__ dinv,
                             float* __restrict__ selfw, int n) {
    int i = blockIdx.x * blockDim.x + threadIdx.x;
    if (i < n) {
        float d = (float)cnt[i] + 2.0f;
        dinv[i] = rsqrtf(d);
        selfw[i] = 2.0f / d;
    }
}

// ---------------- parallel exclusive scan (3 kernels, 512 elems/block) -----------
__global__ __launch_bounds__(256) void scan_part(
    const int* __restrict__ counts, int* __restrict__ offsets,
    int* __restrict__ bsum, int n)
{
    __shared__ int s[512];
    int b = blockIdx.x;
    int base = b * 512;
    int t = threadIdx.x;
    s[t]       = (base + t       < n) ? counts[base + t]       : 0;
    s[t + 256] = (base + t + 256 < n) ? counts[base + t + 256] : 0;

    int offset = 1;
    for (int d = 256; d > 0; d >>= 1) {
        __syncthreads();
        if (t < d) {
            int ai = offset * (2 * t + 1) - 1;
            int bi = offset * (2 * t + 2) - 1;
            s[bi] += s[ai];
        }
        offset <<= 1;
    }
    __syncthreads();
    if (t == 0) { bsum[b] = s[511]; s[511] = 0; }
    for (int d = 1; d < 512; d <<= 1) {
        offset >>= 1;
        __syncthreads();
        if (t < d) {
            int ai = offset * (2 * t + 1) - 1;
            int bi = offset * (2 * t + 2) - 1;
            int tmp = s[ai]; s[ai] = s[bi]; s[bi] += tmp;
        }
    }
    __syncthreads();
    if (base + t < n)       offsets[base + t]       = s[t];
    if (base + t + 256 < n) offsets[base + t + 256] = s[t + 256];
}

__global__ __launch_bounds__(1024) void scan_tops(int* __restrict__ bsum, int nb) {
    __shared__ int s[1024];
    int t = threadIdx.x;
    s[t] = (t < nb) ? bsum[t] : 0;
    __syncthreads();
    for (int off = 1; off < 1024; off <<= 1) {
        int v = (t >= off) ? s[t - off] : 0;
        __syncthreads();
        s[t] += v;
        __syncthreads();
    }
    if (t < nb) bsum[t] = (t == 0) ? 0 : s[t - 1];   // exclusive
}

__global__ __launch_bounds__(256) void scan_add(
    int* __restrict__ offsets, const int* __restrict__ bsum, int n, int e)
{
    int b = blockIdx.x;
    int base = b * 512;
    int add = bsum[b];
    int t = threadIdx.x;
    if (base + t < n)       offsets[base + t]       += add;
    if (base + t + 256 < n) offsets[base + t + 256] += add;
    if (b == 0 && t == 0) offsets[n] = e;
}

__global__ void scatter_edges(const int* __restrict__ rows, const int* __restrict__ cols,
                              const int* __restrict__ offsets, int* __restrict__ cursor,
                              int* __restrict__ src, int e)
{
    int i = blockIdx.x * blockDim.x + threadIdx.x;
    if (i < e) {
        int d = cols[i];
        int pos = offsets[d] + atomicAdd(&cursor[d], 1);
        src[pos] = rows[i];
    }
}

// ---------------- m97-style GEMM: 128x128 tile, global_load_lds staging ----------
// C[M,N] = A[M,K] @ BT^T, BT pre-transposed [N][K]. A rows must be padded to the
// 128-multiple above M (workspace buffers are). 256 threads / 4 waves (2x2).
__global__ __launch_bounds__(256) void gemm_m97(
    const bf16* __restrict__ A, const bf16* __restrict__ BT,
    void* __restrict__ C, const bf16* __restrict__ bias,
    int M, int K, int N, const int* __restrict__ cf32)
{
    __shared__ bf16 As[128 * 32];
    __shared__ bf16 Bs[128 * 32];

    int tid = threadIdx.x;
    int wave = tid >> 6, lane = tid & 63, q = lane >> 4, r = lane & 15;
    int wm = (wave >> 1) * 64, wn = (wave & 1) * 64;
    int m0 = blockIdx.y * 128, n0 = blockIdx.x * 128;
    bool c32 = cf32 && *cf32;

    int lrow = lane >> 2;          // 0..15 row within 16-row chunk
    int lcol = (lane & 3) * 8;     // element col 0/8/16/24

    f32x4 acc[4][4];
#pragma unroll
    for (int mi = 0; mi < 4; mi++)
#pragma unroll
        for (int ni = 0; ni < 4; ni++)
            acc[mi][ni] = {0.f, 0.f, 0.f, 0.f};

    for (int k0 = 0; k0 < K; k0 += 32) {
        // stage A+B tiles direct to LDS: each wave 2 A-chunks + 2 B-chunks (1KB each)
#pragma unroll
        for (int i = 0; i < 2; i++) {
            int c = wave * 2 + i;                      // chunk 0..7 = rows c*16..+15
            const bf16* ga = A  + (size_t)(m0 + c * 16 + lrow) * K + k0 + lcol;
            const bf16* gb = BT + (size_t)(n0 + c * 16 + lrow) * K + k0 + lcol;
            __builtin_amdgcn_global_load_lds(
                (const __attribute__((address_space(1))) unsigned*)ga,
                (__attribute__((address_space(3))) unsigned*)(As + c * 512), 16, 0, 0);
            __builtin_amdgcn_global_load_lds(
                (const __attribute__((address_space(1))) unsigned*)gb,
                (__attribute__((address_space(3))) unsigned*)(Bs + c * 512), 16, 0, 0);
        }
        __syncthreads();

        short8 a[4], b[4];
#pragma unroll
        for (int mi = 0; mi < 4; mi++) a[mi] = *(const short8*)&As[(wm + mi * 16 + r) * 32 + q * 8];
#pragma unroll
        for (int ni = 0; ni < 4; ni++) b[ni] = *(const short8*)&Bs[(wn + ni * 16 + r) * 32 + q * 8];
#pragma unroll
        for (int mi = 0; mi < 4; mi++)
#pragma unroll
            for (int ni = 0; ni < 4; ni++)
                acc[mi][ni] = __builtin_amdgcn_mfma_f32_16x16x32_bf16(a[mi], b[ni], acc[mi][ni], 0, 0, 0);
        __syncthreads();
    }

#pragma unroll
    for (int mi = 0; mi < 4; mi++) {
#pragma unroll
        for (int ni = 0; ni < 4; ni++) {
            int gn = n0 + wn + ni * 16 + r;
            float bv = bias ? __bfloat162float(bias[gn]) : 0.f;
#pragma unroll
            for (int reg = 0; reg < 4; reg++) {
                int gm = m0 + wm + mi * 16 + q * 4 + reg;
                if (gm < M) {
                    float val = acc[mi][ni][reg] + bv;
                    if (c32) ((float*)C)[(size_t)gm * N + gn] = val;
                    else     ((bf16*)C)[(size_t)gm * N + gn] = __float2bfloat16(val);
                }
            }
        }
    }
}

// ---------------- CSR aggregation, 128-dim input (fp32 or bf16 x) -----------------
__global__ __launch_bounds__(256) void agg_csr_din(
    const void* __restrict__ x, const int* __restrict__ offsets,
    const int* __restrict__ src, const float* __restrict__ dinv,
    const float* __restrict__ selfw, bf16* __restrict__ out,
    int n, const int* __restrict__ flags)
{
    int wave = threadIdx.x >> 6, lane = threadIdx.x & 63;
    int dst = blockIdx.x * 4 + wave;
    if (dst >= n) return;
    bool f32 = flags[1] != 0;
    int s0 = offsets[dst], s1 = offsets[dst + 1];
    float di = dinv[dst], sw = selfw[dst];
    float a0, a1;
    if (f32) {
        float2 v = ((const float2*)x)[(size_t)dst * 64 + lane];
        a0 = sw * v.x; a1 = sw * v.y;
    } else {
        unsigned u = ((const unsigned*)x)[(size_t)dst * 64 + lane];
        a0 = sw * bf2f((short)(u & 0xFFFF)); a1 = sw * bf2f((short)(u >> 16));
    }
    for (int p = s0; p < s1; p++) {
        int sr = src[p];
        float nm = di * dinv[sr];
        if (f32) {
            float2 v = ((const float2*)x)[(size_t)sr * 64 + lane];
            a0 += nm * v.x; a1 += nm * v.y;
        } else {
            unsigned u = ((const unsigned*)x)[(size_t)sr * 64 + lane];
            a0 += nm * bf2f((short)(u & 0xFFFF)); a1 += nm * bf2f((short)(u >> 16));
        }
    }
    unsigned o = (unsigned)f2bfbits(a0) | ((unsigned)f2bfbits(a1) << 16);
    ((unsigned*)out)[(size_t)dst * 64 + lane] = o;
}

// ---------------- CSR aggregation, 512-dim bf16 -----------------------------------
__global__ __launch_bounds__(256) void agg_csr(
    const bf16* __restrict__ h, const int* __restrict__ offsets,
    const int* __restrict__ src, const float* __restrict__ dinv,
    const float* __restrict__ selfw, bf16* __restrict__ y, int n)
{
    int wave = threadIdx.x >> 6, lane = threadIdx.x & 63;
    int dst = blockIdx.x * 4 + wave;
    if (dst >= n) return;
    int s0 = offsets[dst], s1 = offsets[dst + 1];
    float di = dinv[dst], sw = selfw[dst];
    short8 hv = *(const short8*)(h + (size_t)dst * HDIM + lane * 8);
    float acc[8];
#pragma unroll
    for (int j = 0; j < 8; j++) acc[j] = sw * bf2f(hv[j]);
    for (int p = s0; p < s1; p++) {
        int sr = src[p];
        float nm = di * dinv[sr];
        short8 v = *(const short8*)(h + (size_t)sr * HDIM + lane * 8);
#pragma unroll
        for (int j = 0; j < 8; j++) acc[j] += nm * bf2f(v[j]);
    }
    short8 o;
#pragma unroll
    for (int j = 0; j < 8; j++) ((bf16*)&o)[j] = __float2bfloat16(acc[j]);
    *(short8*)(y + (size_t)dst * HDIM + lane * 8) = o;
}

// ---------------- BatchNorm stats (vectorized) + coeffs + apply -------------------
// Lane owns 8 consecutive features (16B loads); 4 waves stride rows; LDS cross-wave
// reduction; one atomicAdd per feature per block.
__global__ __launch_bounds__(256) void bn_stats(
    const bf16* __restrict__ y, float* __restrict__ gsum, float* __restrict__ gsq, int n)
{
    __shared__ float red[4][HDIM];   // 8 KB, reused for sum then sq
    int t = threadIdx.x;
    int wave = t >> 6, lane = t & 63;
    int f0 = lane * 8;
    int per = (n + gridDim.x - 1) / gridDim.x;
    int r0 = blockIdx.x * per;
    int r1 = min(r0 + per, n);

    float s[8] = {0, 0, 0, 0, 0, 0, 0, 0};
    float sq[8] = {0, 0, 0, 0, 0, 0, 0, 0};
    for (int r = r0 + wave; r < r1; r += 4) {
        short8 v = *(const short8*)(y + (size_t)r * HDIM + f0);
#pragma unroll
        for (int j = 0; j < 8; j++) {
            float x = bf2f(v[j]);
            s[j] += x; sq[j] += x * x;
        }
    }
#pragma unroll
    for (int j = 0; j < 8; j++) red[wave][f0 + j] = s[j];
    __syncthreads();
    if (wave == 0) {
#pragma unroll
        for (int j = 0; j < 8; j++)
            atomicAdd(&gsum[f0 + j],
                      red[0][f0 + j] + red[1][f0 + j] + red[2][f0 + j] + red[3][f0 + j]);
    }
    __syncthreads();
#pragma unroll
    for (int j = 0; j < 8; j++) red[wave][f0 + j] = sq[j];
    __syncthreads();
    if (wave == 0) {
#pragma unroll
        for (int j = 0; j < 8; j++)
            atomicAdd(&gsq[f0 + j],
                      red[0][f0 + j] + red[1][f0 + j] + red[2][f0 + j] + red[3][f0 + j]);
    }
}

__global__ void bn_final(const float* __restrict__ gsum, const float* __restrict__ gsq,
                         const void* __restrict__ gamma, const void* __restrict__ beta,
                         float* __restrict__ scale, float* __restrict__ shift,
                         float invN, const int* __restrict__ flags)
{
    int f = threadIdx.x;
    float g = flags[1] ? ((const float*)gamma)[f]
                       : __bfloat162float(((const bf16*)gamma)[f]);
    float b = flags[1] ? ((const float*)beta)[f]
                       : __bfloat162float(((const bf16*)beta)[f]);
    float mu = gsum[f] * invN;
    float var = fmaxf(gsq[f] * invN - mu * mu, 0.f);
    float inv = rsqrtf(var + BN_EPS);
    float sc = g * inv;
    scale[f] = sc;
    shift[f] = b - mu * sc;
}

__global__ __launch_bounds__(256) void bn_apply(
    bf16* __restrict__ y, const float* __restrict__ scale,
    const float* __restrict__ shift, long long total8)
{
    long long idx = (long long)blockIdx.x * 256 + threadIdx.x;
    if (idx >= total8) return;
    int f0 = (int)((idx * 8) & (HDIM - 1));
    short8 v = *(const short8*)((const bf16*)y + idx * 8);
    short8 o;
#pragma unroll
    for (int j = 0; j < 8; j++) {
        float val = scale[f0 + j] * bf2f(v[j]) + shift[f0 + j];
        ((bf16*)&o)[j] = __float2bfloat16(val > 0.f ? val : SLOPE * val);
    }
    *(short8*)(y + idx * 8) = o;
}

// ---------------- pooling with fused BN+LeakyReLU (monotone) ----------------------
__global__ __launch_bounds__(512) void pool_fused(
    const bf16* __restrict__ y, const int* __restrict__ batch,
    const float* __restrict__ scale, const float* __restrict__ shift,
    bf16* __restrict__ pooled, int n)
{
    int g = blockIdx.x;
    int f = threadIdx.x;
    int lo = 0, hi = n;
    while (lo < hi) { int mid = (lo + hi) >> 1; if (batch[mid] < g) lo = mid + 1; else hi = mid; }
    int s = lo;
    hi = n;
    while (lo < hi) { int mid = (lo + hi) >> 1; if (batch[mid] <= g) lo = mid + 1; else hi = mid; }
    int e = lo;
    float mx = -3.0e38f, mn = 3.0e38f;
    for (int rr = s; rr < e; rr++) {
        float v = bf2f(__builtin_bit_cast(short, y[(size_t)rr * HDIM + f]));
        mx = fmaxf(mx, v); mn = fminf(mn, v);
    }
    float outv = 0.f;
    if (s < e) {
        float sc = scale[f];
        float t = sc * (sc >= 0.f ? mx : mn) + shift[f];
        outv = t > 0.f ? t : SLOPE * t;
    }
    pooled[(size_t)g * HDIM + f] = __float2bfloat16(outv);
}

// ---------------- orchestration --------------------------------------------------
extern "C" void kernel_launch(void* const* d_in, const int* in_sizes, int n_in,
                              void* d_out, int out_size, void* d_ws, size_t ws_size,
                              hipStream_t stream)
{
    const void* x     = d_in[0];
    const int*  ei    = (const int*)d_in[1];
    const int*  batch = (const int*)d_in[2];
    // d_in[4]=b1, d_in[8]=b2 cancel in training-mode BatchNorm — unused.

    const int N   = in_sizes[2];
    const int E   = in_sizes[1] / 2;
    const int DIN = 128;
    const int OUT = 256;
    const int G   = out_size / OUT;
    const int Mp  = (N + 127) & ~127;   // row-padded for 128-tile staging

    // workspace carve — ~236 MB
    char* p = (char*)d_ws;
    bf16* B1     = (bf16*)p;  p += (size_t)Mp * HDIM * sizeof(bf16);
    bf16* B2     = (bf16*)p;  p += (size_t)Mp * HDIM * sizeof(bf16);
    bf16* Q      = (bf16*)p;  p += (size_t)Mp * DIN * sizeof(bf16);   // aggx; later pooled[G][512]
    bf16* W1T    = (bf16*)p;  p += (size_t)HDIM * DIN * sizeof(bf16);
    bf16* W2T    = (bf16*)p;  p += (size_t)HDIM * HDIM * sizeof(bf16);
    bf16* WfT    = (bf16*)p;  p += (size_t)OUT * HDIM * sizeof(bf16);
    bf16* bfbf   = (bf16*)p;  p += 512 * sizeof(bf16);
    int* ei32    = (int*)p;   p += (size_t)2 * E * sizeof(int);
    int* batch32 = (int*)p;   p += (size_t)N * sizeof(int);
    float* dinv  = (float*)p; p += (size_t)N * sizeof(float);
    float* selfw = (float*)p; p += (size_t)N * sizeof(float);
    int* offsets = (int*)p;   p += (size_t)(N + 4) * sizeof(int);
    int* cursor  = (int*)p;   p += (size_t)N * sizeof(int);
    int* srcarr  = (int*)p;   p += (size_t)E * sizeof(int);
    int* bsum    = (int*)p;   p += 1024 * sizeof(int);
    float* gsum  = (float*)p; p += HDIM * sizeof(float);
    float* gsq   = (float*)p; p += HDIM * sizeof(float);
    float* sc1   = (float*)p; p += HDIM * sizeof(float);
    float* sh1   = (float*)p; p += HDIM * sizeof(float);
    float* sc2   = (float*)p; p += HDIM * sizeof(float);
    float* sh2   = (float*)p; p += HDIM * sizeof(float);
    int* flags   = (int*)p;   p += 4 * sizeof(int);

    // ---- dtype detection + canonicalization ----
    detect_types<<<1, 256, 0, stream>>>(ei, (const unsigned*)x, flags);
    conv_idx<<<(2 * E + 255) / 256, 256, 0, stream>>>(ei, ei32, 2 * E, flags);
    conv_idx<<<(N + 255) / 256, 256, 0, stream>>>(batch, batch32, N, flags);
    wt_conv<<<(DIN * HDIM + 255) / 256, 256, 0, stream>>>(d_in[3], W1T, DIN, HDIM, flags);
    wt_conv<<<(HDIM * HDIM + 255) / 256, 256, 0, stream>>>(d_in[7], W2T, HDIM, HDIM, flags);
    wt_conv<<<(HDIM * OUT + 255) / 256, 256, 0, stream>>>(d_in[11], WfT, HDIM, OUT, flags);
    conv_float<<<1, 256, 0, stream>>>(d_in[12], bfbf, OUT, flags);

    const int* rows = ei32;
    const int* cols = ei32 + E;

    // ---- CSR + degrees (shared by both conv layers) ----
    hipMemsetAsync(cursor, 0, (size_t)N * sizeof(int), stream);
    count_deg<<<(E + 255) / 256, 256, 0, stream>>>(cols, cursor, E);
    finalize_deg<<<(N + 255) / 256, 256, 0, stream>>>(cursor, dinv, selfw, N);
    int nb = (N + 511) / 512;
    scan_part<<<nb, 256, 0, stream>>>(cursor, offsets, bsum, N);
    scan_tops<<<1, 1024, 0, stream>>>(bsum, nb);
    scan_add<<<nb, 256, 0, stream>>>(offsets, bsum, N, E);
    hipMemsetAsync(cursor, 0, (size_t)N * sizeof(int), stream);
    scatter_edges<<<(E + 255) / 256, 256, 0, stream>>>(rows, cols, offsets, cursor, srcarr, E);

    int agg_blocks = (N + 3) / 4;
    long long tot8 = (long long)N * HDIM / 8;
    dim3 g1(HDIM / 128, Mp / 128);

    // ---- layer 1: aggregate x first (agg is linear), then GEMM ----
    agg_csr_din<<<agg_blocks, 256, 0, stream>>>(x, offsets, srcarr, dinv, selfw, Q, N, flags);
    gemm_m97<<<g1, 256, 0, stream>>>(Q, W1T, B2, nullptr, N, DIN, HDIM, nullptr);
    hipMemsetAsync(gsum, 0, 2 * HDIM * sizeof(float), stream);   // gsum+gsq contiguous
    bn_stats<<<512, 256, 0, stream>>>(B2, gsum, gsq, N);
    bn_final<<<1, HDIM, 0, stream>>>(gsum, gsq, d_in[5], d_in[6], sc1, sh1, 1.0f / N, flags);
    bn_apply<<<(int)((tot8 + 255) / 256), 256, 0, stream>>>(B2, sc1, sh1, tot8);

    // ---- layer 2: GEMM, then aggregate ----
    gemm_m97<<<g1, 256, 0, stream>>>(B2, W2T, B1, nullptr, N, HDIM, HDIM, nullptr);
    agg_csr<<<agg_blocks, 256, 0, stream>>>(B1, offsets, srcarr, dinv, selfw, B2, N);
    hipMemsetAsync(gsum, 0, 2 * HDIM * sizeof(float), stream);
    bn_stats<<<512, 256, 0, stream>>>(B2, gsum, gsq, N);
    bn_final<<<1, HDIM, 0, stream>>>(gsum, gsq, d_in[9], d_in[10], sc2, sh2, 1.0f / N, flags);

    // ---- pool (fused BN+leaky, monotone) + head GEMM ----
    pool_fused<<<G, HDIM, 0, stream>>>(B2, batch32, sc2, sh2, Q, N);
    gemm_m97<<<dim3(OUT / 128, G / 128), 256, 0, stream>>>(
        Q, WfT, d_out, bfbf, G, HDIM, OUT, flags + 1);
}

// Round 10
// 806.320 us; speedup vs baseline: 1.0393x; 1.0393x over previous
//
#include <hip/hip_runtime.h>
#include <hip/hip_bf16.h>

typedef __hip_bfloat16 bf16;
typedef __attribute__((ext_vector_type(8))) short short8;
typedef __attribute__((ext_vector_type(4))) float f32x4;

#define HDIM 512
#define SLOPE 0.01f
#define BN_EPS 1e-5f
#define STRIPES 8

__device__ inline float bf2f(short s) {
    unsigned u = ((unsigned)(unsigned short)s) << 16;
    return __builtin_bit_cast(float, u);
}
__device__ inline unsigned short f2bfbits(float v) {
    bf16 h = __float2bfloat16(v);
    return (unsigned short)__builtin_bit_cast(short, h);
}

// ---------------- runtime dtype detection ----------------
// flags[0]=1 if indices int64; flags[1]=1 if float tensors fp32.
__global__ void detect_types(const int* __restrict__ ei, const unsigned* __restrict__ xw,
                             int* __restrict__ flags) {
    __shared__ int nzhi, okbf;
    if (threadIdx.x == 0) { nzhi = 0; okbf = 0; }
    __syncthreads();
    int lo = 0, ok = 0;
    for (int i = threadIdx.x; i < 2048; i += 256)
        if (ei[2 * i + 1] != 0) lo++;
    for (int i = threadIdx.x; i < 1024; i += 256) {
        unsigned w = (xw[i] & 0xFFFFu) << 16;
        float av = fabsf(__builtin_bit_cast(float, w));
        if (av > 0.0009f && av < 64.0f) ok++;
    }
    if (lo) atomicAdd(&nzhi, lo);
    if (ok) atomicAdd(&okbf, ok);
    __syncthreads();
    if (threadIdx.x == 0) {
        flags[0] = (nzhi == 0) ? 1 : 0;
        flags[1] = (okbf < 512) ? 1 : 0;
    }
}

__global__ void conv_idx(const int* __restrict__ src, int* __restrict__ dst, int n,
                         const int* __restrict__ flags) {
    int i = blockIdx.x * blockDim.x + threadIdx.x;
    if (i < n) dst[i] = flags[0] ? (int)((const long long*)src)[i] : src[i];
}

__global__ void conv_float(const void* __restrict__ src, bf16* __restrict__ dst, int n,
                           const int* __restrict__ flags) {
    int i = blockIdx.x * blockDim.x + threadIdx.x;
    if (i < n)
        dst[i] = flags[1] ? __float2bfloat16(((const float*)src)[i])
                          : ((const bf16*)src)[i];
}

// transpose + convert weight: WT[nn][k] = W[k][nn]  (W is [K][Nn])
__global__ void wt_conv(const void* __restrict__ W, bf16* __restrict__ WT,
                        int K, int Nn, const int* __restrict__ flags) {
    int idx = blockIdx.x * 256 + threadIdx.x;
    if (idx >= K * Nn) return;
    int nn = idx / K;
    int k = idx - nn * K;
    float v = flags[1] ? ((const float*)W)[(size_t)k * Nn + nn]
                       : __bfloat162float(((const bf16*)W)[(size_t)k * Nn + nn]);
    WT[idx] = __float2bfloat16(v);
}

// ---------------- degree + CSR build ----------------
__global__ void count_deg(const int* __restrict__ col, int* __restrict__ cnt, int e) {
    int i = blockIdx.x * blockDim.x + threadIdx.x;
    if (i < e) atomicAdd(&cnt[col[i]], 1);
}

__global__ void finalize_deg(const int* __restrict__ cnt, float* __restrict__ dinv,
                             float* __restrict__ selfw, int n) {
    int i = blockIdx.x * blockDim.x + threadIdx.x;
    if (i < n) {
        float d = (float)cnt[i] + 2.0f;
        dinv[i] = rsqrtf(d);
        selfw[i] = 2.0f / d;
    }
}

// ---------------- parallel exclusive scan (3 kernels, 512 elems/block) -----------
__global__ __launch_bounds__(256) void scan_part(
    const int* __restrict__ counts, int* __restrict__ offsets,
    int* __restrict__ bsum, int n)
{
    __shared__ int s[512];
    int b = blockIdx.x;
    int base = b * 512;
    int t = threadIdx.x;
    s[t]       = (base + t       < n) ? counts[base + t]       : 0;
    s[t + 256] = (base + t + 256 < n) ? counts[base + t + 256] : 0;

    int offset = 1;
    for (int d = 256; d > 0; d >>= 1) {
        __syncthreads();
        if (t < d) {
            int ai = offset * (2 * t + 1) - 1;
            int bi = offset * (2 * t + 2) - 1;
            s[bi] += s[ai];
        }
        offset <<= 1;
    }
    __syncthreads();
    if (t == 0) { bsum[b] = s[511]; s[511] = 0; }
    for (int d = 1; d < 512; d <<= 1) {
        offset >>= 1;
        __syncthreads();
        if (t < d) {
            int ai = offset * (2 * t + 1) - 1;
            int bi = offset * (2 * t + 2) - 1;
            int tmp = s[ai]; s[ai] = s[bi]; s[bi] += tmp;
        }
    }
    __syncthreads();
    if (base + t < n)       offsets[base + t]       = s[t];
    if (base + t + 256 < n) offsets[base + t + 256] = s[t + 256];
}

__global__ __launch_bounds__(1024) void scan_tops(int* __restrict__ bsum, int nb) {
    __shared__ int s[1024];
    int t = threadIdx.x;
    s[t] = (t < nb) ? bsum[t] : 0;
    __syncthreads();
    for (int off = 1; off < 1024; off <<= 1) {
        int v = (t >= off) ? s[t - off] : 0;
        __syncthreads();
        s[t] += v;
        __syncthreads();
    }
    if (t < nb) bsum[t] = (t == 0) ? 0 : s[t - 1];   // exclusive
}

__global__ __launch_bounds__(256) void scan_add(
    int* __restrict__ offsets, const int* __restrict__ bsum, int n, int e)
{
    int b = blockIdx.x;
    int base = b * 512;
    int add = bsum[b];
    int t = threadIdx.x;
    if (base + t < n)       offsets[base + t]       += add;
    if (base + t + 256 < n) offsets[base + t + 256] += add;
    if (b == 0 && t == 0) offsets[n] = e;
}

__global__ void scatter_edges(const int* __restrict__ rows, const int* __restrict__ cols,
                              const int* __restrict__ offsets, int* __restrict__ cursor,
                              int* __restrict__ src, int e)
{
    int i = blockIdx.x * blockDim.x + threadIdx.x;
    if (i < e) {
        int d = cols[i];
        int pos = offsets[d] + atomicAdd(&cursor[d], 1);
        src[pos] = rows[i];
    }
}

// ---------------- m97-style GEMM: 128x128 tile, global_load_lds staging ----------
// C[M,N] = A[M,K] @ BT^T, BT pre-transposed [N][K]. A rows must be padded to the
// 128-multiple above M (workspace buffers are). 256 threads / 4 waves (2x2).
__global__ __launch_bounds__(256) void gemm_m97(
    const bf16* __restrict__ A, const bf16* __restrict__ BT,
    void* __restrict__ C, const bf16* __restrict__ bias,
    int M, int K, int N, const int* __restrict__ cf32)
{
    __shared__ bf16 As[128 * 32];
    __shared__ bf16 Bs[128 * 32];

    int tid = threadIdx.x;
    int wave = tid >> 6, lane = tid & 63, q = lane >> 4, r = lane & 15;
    int wm = (wave >> 1) * 64, wn = (wave & 1) * 64;
    int m0 = blockIdx.y * 128, n0 = blockIdx.x * 128;
    bool c32 = cf32 && *cf32;

    int lrow = lane >> 2;          // 0..15 row within 16-row chunk
    int lcol = (lane & 3) * 8;     // element col 0/8/16/24

    f32x4 acc[4][4];
#pragma unroll
    for (int mi = 0; mi < 4; mi++)
#pragma unroll
        for (int ni = 0; ni < 4; ni++)
            acc[mi][ni] = {0.f, 0.f, 0.f, 0.f};

    for (int k0 = 0; k0 < K; k0 += 32) {
        // stage A+B tiles direct to LDS: each wave 2 A-chunks + 2 B-chunks (1KB each)
#pragma unroll
        for (int i = 0; i < 2; i++) {
            int c = wave * 2 + i;                      // chunk 0..7 = rows c*16..+15
            const bf16* ga = A  + (size_t)(m0 + c * 16 + lrow) * K + k0 + lcol;
            const bf16* gb = BT + (size_t)(n0 + c * 16 + lrow) * K + k0 + lcol;
            __builtin_amdgcn_global_load_lds(
                (const __attribute__((address_space(1))) unsigned*)ga,
                (__attribute__((address_space(3))) unsigned*)(As + c * 512), 16, 0, 0);
            __builtin_amdgcn_global_load_lds(
                (const __attribute__((address_space(1))) unsigned*)gb,
                (__attribute__((address_space(3))) unsigned*)(Bs + c * 512), 16, 0, 0);
        }
        __syncthreads();

        short8 a[4], b[4];
#pragma unroll
        for (int mi = 0; mi < 4; mi++) a[mi] = *(const short8*)&As[(wm + mi * 16 + r) * 32 + q * 8];
#pragma unroll
        for (int ni = 0; ni < 4; ni++) b[ni] = *(const short8*)&Bs[(wn + ni * 16 + r) * 32 + q * 8];
#pragma unroll
        for (int mi = 0; mi < 4; mi++)
#pragma unroll
            for (int ni = 0; ni < 4; ni++)
                acc[mi][ni] = __builtin_amdgcn_mfma_f32_16x16x32_bf16(a[mi], b[ni], acc[mi][ni], 0, 0, 0);
        __syncthreads();
    }

#pragma unroll
    for (int mi = 0; mi < 4; mi++) {
#pragma unroll
        for (int ni = 0; ni < 4; ni++) {
            int gn = n0 + wn + ni * 16 + r;
            float bv = bias ? __bfloat162float(bias[gn]) : 0.f;
#pragma unroll
            for (int reg = 0; reg < 4; reg++) {
                int gm = m0 + wm + mi * 16 + q * 4 + reg;
                if (gm < M) {
                    float val = acc[mi][ni][reg] + bv;
                    if (c32) ((float*)C)[(size_t)gm * N + gn] = val;
                    else     ((bf16*)C)[(size_t)gm * N + gn] = __float2bfloat16(val);
                }
            }
        }
    }
}

// ---------------- CSR aggregation, 128-dim input (fp32 or bf16 x) -----------------
__global__ __launch_bounds__(256) void agg_csr_din(
    const void* __restrict__ x, const int* __restrict__ offsets,
    const int* __restrict__ src, const float* __restrict__ dinv,
    const float* __restrict__ selfw, bf16* __restrict__ out,
    int n, const int* __restrict__ flags)
{
    int wave = threadIdx.x >> 6, lane = threadIdx.x & 63;
    int dst = blockIdx.x * 4 + wave;
    if (dst >= n) return;
    bool f32 = flags[1] != 0;
    int s0 = offsets[dst], s1 = offsets[dst + 1];
    float di = dinv[dst], sw = selfw[dst];
    float a0, a1;
    if (f32) {
        float2 v = ((const float2*)x)[(size_t)dst * 64 + lane];
        a0 = sw * v.x; a1 = sw * v.y;
    } else {
        unsigned u = ((const unsigned*)x)[(size_t)dst * 64 + lane];
        a0 = sw * bf2f((short)(u & 0xFFFF)); a1 = sw * bf2f((short)(u >> 16));
    }
    for (int p = s0; p < s1; p++) {
        int sr = src[p];
        float nm = di * dinv[sr];
        if (f32) {
            float2 v = ((const float2*)x)[(size_t)sr * 64 + lane];
            a0 += nm * v.x; a1 += nm * v.y;
        } else {
            unsigned u = ((const unsigned*)x)[(size_t)sr * 64 + lane];
            a0 += nm * bf2f((short)(u & 0xFFFF)); a1 += nm * bf2f((short)(u >> 16));
        }
    }
    unsigned o = (unsigned)f2bfbits(a0) | ((unsigned)f2bfbits(a1) << 16);
    ((unsigned*)out)[(size_t)dst * 64 + lane] = o;
}

// ---------------- CSR aggregation, 512-dim bf16 -----------------------------------
__global__ __launch_bounds__(256) void agg_csr(
    const bf16* __restrict__ h, const int* __restrict__ offsets,
    const int* __restrict__ src, const float* __restrict__ dinv,
    const float* __restrict__ selfw, bf16* __restrict__ y, int n)
{
    int wave = threadIdx.x >> 6, lane = threadIdx.x & 63;
    int dst = blockIdx.x * 4 + wave;
    if (dst >= n) return;
    int s0 = offsets[dst], s1 = offsets[dst + 1];
    float di = dinv[dst], sw = selfw[dst];
    short8 hv = *(const short8*)(h + (size_t)dst * HDIM + lane * 8);
    float acc[8];
#pragma unroll
    for (int j = 0; j < 8; j++) acc[j] = sw * bf2f(hv[j]);
    for (int p = s0; p < s1; p++) {
        int sr = src[p];
        float nm = di * dinv[sr];
        short8 v = *(const short8*)(h + (size_t)sr * HDIM + lane * 8);
#pragma unroll
        for (int j = 0; j < 8; j++) acc[j] += nm * bf2f(v[j]);
    }
    short8 o;
#pragma unroll
    for (int j = 0; j < 8; j++) ((bf16*)&o)[j] = __float2bfloat16(acc[j]);
    *(short8*)(y + (size_t)dst * HDIM + lane * 8) = o;
}

// ---------------- BatchNorm stats v3: wave-stride grid, 2x unroll, striped atomics
// gpart layout: [STRIPES][2][HDIM] (sum plane, sq plane per stripe).
__global__ __launch_bounds__(256) void bn_stats(
    const bf16* __restrict__ y, float* __restrict__ gpart, int n)
{
    __shared__ float red[4][HDIM];
    int t = threadIdx.x;
    int wave = t >> 6, lane = t & 63;
    int f0 = lane * 8;
    int gw = blockIdx.x * 4 + wave;      // global wave id
    int nw = gridDim.x * 4;

    float s[8] = {0, 0, 0, 0, 0, 0, 0, 0};
    float sq[8] = {0, 0, 0, 0, 0, 0, 0, 0};
    int r = gw;
    for (; r + nw < n; r += 2 * nw) {    // 2 independent loads in flight
        short8 v0 = *(const short8*)(y + (size_t)r * HDIM + f0);
        short8 v1 = *(const short8*)(y + (size_t)(r + nw) * HDIM + f0);
#pragma unroll
        for (int j = 0; j < 8; j++) {
            float x0 = bf2f(v0[j]), x1 = bf2f(v1[j]);
            s[j] += x0 + x1; sq[j] += x0 * x0 + x1 * x1;
        }
    }
    if (r < n) {
        short8 v0 = *(const short8*)(y + (size_t)r * HDIM + f0);
#pragma unroll
        for (int j = 0; j < 8; j++) { float x0 = bf2f(v0[j]); s[j] += x0; sq[j] += x0 * x0; }
    }

#pragma unroll
    for (int j = 0; j < 8; j++) red[wave][f0 + j] = s[j];
    __syncthreads();
    float* base = gpart + (size_t)(blockIdx.x & (STRIPES - 1)) * 2 * HDIM;
    if (wave == 0) {
#pragma unroll
        for (int j = 0; j < 8; j++)
            atomicAdd(&base[f0 + j],
                      red[0][f0 + j] + red[1][f0 + j] + red[2][f0 + j] + red[3][f0 + j]);
    }
    __syncthreads();
#pragma unroll
    for (int j = 0; j < 8; j++) red[wave][f0 + j] = sq[j];
    __syncthreads();
    if (wave == 0) {
#pragma unroll
        for (int j = 0; j < 8; j++)
            atomicAdd(&base[HDIM + f0 + j],
                      red[0][f0 + j] + red[1][f0 + j] + red[2][f0 + j] + red[3][f0 + j]);
    }
}

__global__ void bn_final(const float* __restrict__ gpart,
                         const void* __restrict__ gamma, const void* __restrict__ beta,
                         float* __restrict__ scale, float* __restrict__ shift,
                         float invN, const int* __restrict__ flags)
{
    int f = threadIdx.x;
    float s = 0.f, q = 0.f;
#pragma unroll
    for (int k = 0; k < STRIPES; k++) {
        s += gpart[(size_t)k * 2 * HDIM + f];
        q += gpart[(size_t)k * 2 * HDIM + HDIM + f];
    }
    float g = flags[1] ? ((const float*)gamma)[f]
                       : __bfloat162float(((const bf16*)gamma)[f]);
    float b = flags[1] ? ((const float*)beta)[f]
                       : __bfloat162float(((const bf16*)beta)[f]);
    float mu = s * invN;
    float var = fmaxf(q * invN - mu * mu, 0.f);
    float inv = rsqrtf(var + BN_EPS);
    float sc = g * inv;
    scale[f] = sc;
    shift[f] = b - mu * sc;
}

__global__ __launch_bounds__(256) void bn_apply(
    bf16* __restrict__ y, const float* __restrict__ scale,
    const float* __restrict__ shift, long long total8)
{
    long long idx = (long long)blockIdx.x * 256 + threadIdx.x;
    if (idx >= total8) return;
    int f0 = (int)((idx * 8) & (HDIM - 1));
    short8 v = *(const short8*)((const bf16*)y + idx * 8);
    short8 o;
#pragma unroll
    for (int j = 0; j < 8; j++) {
        float val = scale[f0 + j] * bf2f(v[j]) + shift[f0 + j];
        ((bf16*)&o)[j] = __float2bfloat16(val > 0.f ? val : SLOPE * val);
    }
    *(short8*)(y + idx * 8) = o;
}

// ---------------- pooling with fused BN+LeakyReLU (monotone) ----------------------
__global__ __launch_bounds__(512) void pool_fused(
    const bf16* __restrict__ y, const int* __restrict__ batch,
    const float* __restrict__ scale, const float* __restrict__ shift,
    bf16* __restrict__ pooled, int n)
{
    int g = blockIdx.x;
    int f = threadIdx.x;
    int lo = 0, hi = n;
    while (lo < hi) { int mid = (lo + hi) >> 1; if (batch[mid] < g) lo = mid + 1; else hi = mid; }
    int s = lo;
    hi = n;
    while (lo < hi) { int mid = (lo + hi) >> 1; if (batch[mid] <= g) lo = mid + 1; else hi = mid; }
    int e = lo;
    float mx = -3.0e38f, mn = 3.0e38f;
    for (int rr = s; rr < e; rr++) {
        float v = bf2f(__builtin_bit_cast(short, y[(size_t)rr * HDIM + f]));
        mx = fmaxf(mx, v); mn = fminf(mn, v);
    }
    float outv = 0.f;
    if (s < e) {
        float sc = scale[f];
        float t = sc * (sc >= 0.f ? mx : mn) + shift[f];
        outv = t > 0.f ? t : SLOPE * t;
    }
    pooled[(size_t)g * HDIM + f] = __float2bfloat16(outv);
}

// ---------------- orchestration --------------------------------------------------
extern "C" void kernel_launch(void* const* d_in, const int* in_sizes, int n_in,
                              void* d_out, int out_size, void* d_ws, size_t ws_size,
                              hipStream_t stream)
{
    const void* x     = d_in[0];
    const int*  ei    = (const int*)d_in[1];
    const int*  batch = (const int*)d_in[2];
    // d_in[4]=b1, d_in[8]=b2 cancel in training-mode BatchNorm — unused.

    const int N   = in_sizes[2];
    const int E   = in_sizes[1] / 2;
    const int DIN = 128;
    const int OUT = 256;
    const int G   = out_size / OUT;
    const int Mp  = (N + 127) & ~127;   // row-padded for 128-tile staging

    // workspace carve — ~236 MB
    char* p = (char*)d_ws;
    bf16* B1     = (bf16*)p;  p += (size_t)Mp * HDIM * sizeof(bf16);
    bf16* B2     = (bf16*)p;  p += (size_t)Mp * HDIM * sizeof(bf16);
    bf16* Q      = (bf16*)p;  p += (size_t)Mp * DIN * sizeof(bf16);   // aggx; later pooled[G][512]
    bf16* W1T    = (bf16*)p;  p += (size_t)HDIM * DIN * sizeof(bf16);
    bf16* W2T    = (bf16*)p;  p += (size_t)HDIM * HDIM * sizeof(bf16);
    bf16* WfT    = (bf16*)p;  p += (size_t)OUT * HDIM * sizeof(bf16);
    bf16* bfbf   = (bf16*)p;  p += 512 * sizeof(bf16);
    int* ei32    = (int*)p;   p += (size_t)2 * E * sizeof(int);
    int* batch32 = (int*)p;   p += (size_t)N * sizeof(int);
    float* dinv  = (float*)p; p += (size_t)N * sizeof(float);
    float* selfw = (float*)p; p += (size_t)N * sizeof(float);
    int* offsets = (int*)p;   p += (size_t)(N + 4) * sizeof(int);
    int* cursor  = (int*)p;   p += (size_t)N * sizeof(int);
    int* srcarr  = (int*)p;   p += (size_t)E * sizeof(int);
    int* bsum    = (int*)p;   p += 1024 * sizeof(int);
    float* gpart = (float*)p; p += (size_t)STRIPES * 2 * HDIM * sizeof(float);
    float* sc1   = (float*)p; p += HDIM * sizeof(float);
    float* sh1   = (float*)p; p += HDIM * sizeof(float);
    float* sc2   = (float*)p; p += HDIM * sizeof(float);
    float* sh2   = (float*)p; p += HDIM * sizeof(float);
    int* flags   = (int*)p;   p += 4 * sizeof(int);

    // ---- dtype detection + canonicalization ----
    detect_types<<<1, 256, 0, stream>>>(ei, (const unsigned*)x, flags);
    conv_idx<<<(2 * E + 255) / 256, 256, 0, stream>>>(ei, ei32, 2 * E, flags);
    conv_idx<<<(N + 255) / 256, 256, 0, stream>>>(batch, batch32, N, flags);
    wt_conv<<<(DIN * HDIM + 255) / 256, 256, 0, stream>>>(d_in[3], W1T, DIN, HDIM, flags);
    wt_conv<<<(HDIM * HDIM + 255) / 256, 256, 0, stream>>>(d_in[7], W2T, HDIM, HDIM, flags);
    wt_conv<<<(HDIM * OUT + 255) / 256, 256, 0, stream>>>(d_in[11], WfT, HDIM, OUT, flags);
    conv_float<<<1, 256, 0, stream>>>(d_in[12], bfbf, OUT, flags);

    const int* rows = ei32;
    const int* cols = ei32 + E;

    // ---- CSR + degrees (shared by both conv layers) ----
    hipMemsetAsync(cursor, 0, (size_t)N * sizeof(int), stream);
    count_deg<<<(E + 255) / 256, 256, 0, stream>>>(cols, cursor, E);
    finalize_deg<<<(N + 255) / 256, 256, 0, stream>>>(cursor, dinv, selfw, N);
    int nb = (N + 511) / 512;
    scan_part<<<nb, 256, 0, stream>>>(cursor, offsets, bsum, N);
    scan_tops<<<1, 1024, 0, stream>>>(bsum, nb);
    scan_add<<<nb, 256, 0, stream>>>(offsets, bsum, N, E);
    hipMemsetAsync(cursor, 0, (size_t)N * sizeof(int), stream);
    scatter_edges<<<(E + 255) / 256, 256, 0, stream>>>(rows, cols, offsets, cursor, srcarr, E);

    int agg_blocks = (N + 3) / 4;
    long long tot8 = (long long)N * HDIM / 8;
    dim3 g1(HDIM / 128, Mp / 128);
    size_t gpart_bytes = (size_t)STRIPES * 2 * HDIM * sizeof(float);

    // ---- layer 1: aggregate x first (agg is linear), then GEMM ----
    agg_csr_din<<<agg_blocks, 256, 0, stream>>>(x, offsets, srcarr, dinv, selfw, Q, N, flags);
    gemm_m97<<<g1, 256, 0, stream>>>(Q, W1T, B2, nullptr, N, DIN, HDIM, nullptr);
    hipMemsetAsync(gpart, 0, gpart_bytes, stream);
    bn_stats<<<2048, 256, 0, stream>>>(B2, gpart, N);
    bn_final<<<1, HDIM, 0, stream>>>(gpart, d_in[5], d_in[6], sc1, sh1, 1.0f / N, flags);
    bn_apply<<<(int)((tot8 + 255) / 256), 256, 0, stream>>>(B2, sc1, sh1, tot8);

    // ---- layer 2: GEMM, then aggregate ----
    gemm_m97<<<g1, 256, 0, stream>>>(B2, W2T, B1, nullptr, N, HDIM, HDIM, nullptr);
    agg_csr<<<agg_blocks, 256, 0, stream>>>(B1, offsets, srcarr, dinv, selfw, B2, N);
    hipMemsetAsync(gpart, 0, gpart_bytes, stream);
    bn_stats<<<2048, 256, 0, stream>>>(B2, gpart, N);
    bn_final<<<1, HDIM, 0, stream>>>(gpart, d_in[9], d_in[10], sc2, sh2, 1.0f / N, flags);

    // ---- pool (fused BN+leaky, monotone) + head GEMM ----
    pool_fused<<<G, HDIM, 0, stream>>>(B2, batch32, sc2, sh2, Q, N);
    gemm_m97<<<dim3(OUT / 128, G / 128), 256, 0, stream>>>(
        Q, WfT, d_out, bfbf, G, HDIM, OUT, flags + 1);
}

// Round 11
// 697.218 us; speedup vs baseline: 1.2020x; 1.1565x over previous
//
#include <hip/hip_runtime.h>
#include <hip/hip_bf16.h>

typedef __hip_bfloat16 bf16;
typedef __attribute__((ext_vector_type(8))) short short8;
typedef __attribute__((ext_vector_type(4))) float f32x4;

#define HDIM 512
#define SLOPE 0.01f
#define BN_EPS 1e-5f
#define STRIPES 8

__device__ inline float bf2f(short s) {
    unsigned u = ((unsigned)(unsigned short)s) << 16;
    return __builtin_bit_cast(float, u);
}
__device__ inline unsigned short f2bfbits(float v) {
    bf16 h = __float2bfloat16(v);
    return (unsigned short)__builtin_bit_cast(short, h);
}

// ---------------- runtime dtype detection ----------------
__global__ void detect_types(const int* __restrict__ ei, const unsigned* __restrict__ xw,
                             int* __restrict__ flags) {
    __shared__ int nzhi, okbf;
    if (threadIdx.x == 0) { nzhi = 0; okbf = 0; }
    __syncthreads();
    int lo = 0, ok = 0;
    for (int i = threadIdx.x; i < 2048; i += 256)
        if (ei[2 * i + 1] != 0) lo++;
    for (int i = threadIdx.x; i < 1024; i += 256) {
        unsigned w = (xw[i] & 0xFFFFu) << 16;
        float av = fabsf(__builtin_bit_cast(float, w));
        if (av > 0.0009f && av < 64.0f) ok++;
    }
    if (lo) atomicAdd(&nzhi, lo);
    if (ok) atomicAdd(&okbf, ok);
    __syncthreads();
    if (threadIdx.x == 0) {
        flags[0] = (nzhi == 0) ? 1 : 0;
        flags[1] = (okbf < 512) ? 1 : 0;
    }
}

__global__ void conv_idx(const int* __restrict__ src, int* __restrict__ dst, int n,
                         const int* __restrict__ flags) {
    int i = blockIdx.x * blockDim.x + threadIdx.x;
    if (i < n) dst[i] = flags[0] ? (int)((const long long*)src)[i] : src[i];
}

__global__ void conv_float(const void* __restrict__ src, bf16* __restrict__ dst, int n,
                           const int* __restrict__ flags) {
    int i = blockIdx.x * blockDim.x + threadIdx.x;
    if (i < n)
        dst[i] = flags[1] ? __float2bfloat16(((const float*)src)[i])
                          : ((const bf16*)src)[i];
}

// transpose + convert weight: WT[nn][k] = W[k][nn]  (W is [K][Nn])
__global__ void wt_conv(const void* __restrict__ W, bf16* __restrict__ WT,
                        int K, int Nn, const int* __restrict__ flags) {
    int idx = blockIdx.x * 256 + threadIdx.x;
    if (idx >= K * Nn) return;
    int nn = idx / K;
    int k = idx - nn * K;
    float v = flags[1] ? ((const float*)W)[(size_t)k * Nn + nn]
                       : __bfloat162float(((const bf16*)W)[(size_t)k * Nn + nn]);
    WT[idx] = __float2bfloat16(v);
}

// ---------------- degree + CSR build ----------------
__global__ void count_deg(const int* __restrict__ col, int* __restrict__ cnt, int e) {
    int i = blockIdx.x * blockDim.x + threadIdx.x;
    if (i < e) atomicAdd(&cnt[col[i]], 1);
}

__global__ void finalize_deg(const int* __restrict__ cnt, float* __restrict__ dinv,
                             float* __restrict__ selfw, int n) {
    int i = blockIdx.x * blockDim.x + threadIdx.x;
    if (i < n) {
        float d = (float)cnt[i] + 2.0f;
        dinv[i] = rsqrtf(d);
        selfw[i] = 2.0f / d;
    }
}

// ---------------- parallel exclusive scan (3 kernels, 512 elems/block) -----------
__global__ __launch_bounds__(256) void scan_part(
    const int* __restrict__ counts, int* __restrict__ offsets,
    int* __restrict__ bsum, int n)
{
    __shared__ int s[512];
    int b = blockIdx.x;
    int base = b * 512;
    int t = threadIdx.x;
    s[t]       = (base + t       < n) ? counts[base + t]       : 0;
    s[t + 256] = (base + t + 256 < n) ? counts[base + t + 256] : 0;

    int offset = 1;
    for (int d = 256; d > 0; d >>= 1) {
        __syncthreads();
        if (t < d) {
            int ai = offset * (2 * t + 1) - 1;
            int bi = offset * (2 * t + 2) - 1;
            s[bi] += s[ai];
        }
        offset <<= 1;
    }
    __syncthreads();
    if (t == 0) { bsum[b] = s[511]; s[511] = 0; }
    for (int d = 1; d < 512; d <<= 1) {
        offset >>= 1;
        __syncthreads();
        if (t < d) {
            int ai = offset * (2 * t + 1) - 1;
            int bi = offset * (2 * t + 2) - 1;
            int tmp = s[ai]; s[ai] = s[bi]; s[bi] += tmp;
        }
    }
    __syncthreads();
    if (base + t < n)       offsets[base + t]       = s[t];
    if (base + t + 256 < n) offsets[base + t + 256] = s[t + 256];
}

__global__ __launch_bounds__(1024) void scan_tops(int* __restrict__ bsum, int nb) {
    __shared__ int s[1024];
    int t = threadIdx.x;
    s[t] = (t < nb) ? bsum[t] : 0;
    __syncthreads();
    for (int off = 1; off < 1024; off <<= 1) {
        int v = (t >= off) ? s[t - off] : 0;
        __syncthreads();
        s[t] += v;
        __syncthreads();
    }
    if (t < nb) bsum[t] = (t == 0) ? 0 : s[t - 1];   // exclusive
}

__global__ __launch_bounds__(256) void scan_add(
    int* __restrict__ offsets, const int* __restrict__ bsum, int n, int e)
{
    int b = blockIdx.x;
    int base = b * 512;
    int add = bsum[b];
    int t = threadIdx.x;
    if (base + t < n)       offsets[base + t]       += add;
    if (base + t + 256 < n) offsets[base + t + 256] += add;
    if (b == 0 && t == 0) offsets[n] = e;
}

__global__ void scatter_edges(const int* __restrict__ rows, const int* __restrict__ cols,
                              const int* __restrict__ offsets, int* __restrict__ cursor,
                              int* __restrict__ src, int e)
{
    int i = blockIdx.x * blockDim.x + threadIdx.x;
    if (i < e) {
        int d = cols[i];
        int pos = offsets[d] + atomicAdd(&cursor[d], 1);
        src[pos] = rows[i];
    }
}

// ---------------- m97-style GEMM + optional fused BN-stats epilogue ---------------
// C[M,N] = A[M,K] @ BT^T, BT pre-transposed [N][K]. Rows padded to 128.
// STATS: per-feature sum/sumsq of fp32 accs (rows < M) -> striped gpart[s][2][HDIM].
template<bool STATS>
__global__ __launch_bounds__(256) void gemm_m97(
    const bf16* __restrict__ A, const bf16* __restrict__ BT,
    void* __restrict__ C, const bf16* __restrict__ bias,
    int M, int K, int N, const int* __restrict__ cf32,
    float* __restrict__ gpart)
{
    __shared__ bf16 As[128 * 32];
    __shared__ bf16 Bs[128 * 32];
    __shared__ float ssum[STATS ? 128 : 1];
    __shared__ float ssq[STATS ? 128 : 1];

    int tid = threadIdx.x;
    int wave = tid >> 6, lane = tid & 63, q = lane >> 4, r = lane & 15;
    int wm = (wave >> 1) * 64, wn = (wave & 1) * 64;
    int m0 = blockIdx.y * 128, n0 = blockIdx.x * 128;
    bool c32 = cf32 && *cf32;

    if constexpr (STATS) {
        if (tid < 128) { ssum[tid] = 0.f; ssq[tid] = 0.f; }
    }

    int lrow = lane >> 2;
    int lcol = (lane & 3) * 8;

    f32x4 acc[4][4];
#pragma unroll
    for (int mi = 0; mi < 4; mi++)
#pragma unroll
        for (int ni = 0; ni < 4; ni++)
            acc[mi][ni] = {0.f, 0.f, 0.f, 0.f};

    for (int k0 = 0; k0 < K; k0 += 32) {
#pragma unroll
        for (int i = 0; i < 2; i++) {
            int c = wave * 2 + i;
            const bf16* ga = A  + (size_t)(m0 + c * 16 + lrow) * K + k0 + lcol;
            const bf16* gb = BT + (size_t)(n0 + c * 16 + lrow) * K + k0 + lcol;
            __builtin_amdgcn_global_load_lds(
                (const __attribute__((address_space(1))) unsigned*)ga,
                (__attribute__((address_space(3))) unsigned*)(As + c * 512), 16, 0, 0);
            __builtin_amdgcn_global_load_lds(
                (const __attribute__((address_space(1))) unsigned*)gb,
                (__attribute__((address_space(3))) unsigned*)(Bs + c * 512), 16, 0, 0);
        }
        __syncthreads();

        short8 a[4], b[4];
#pragma unroll
        for (int mi = 0; mi < 4; mi++) a[mi] = *(const short8*)&As[(wm + mi * 16 + r) * 32 + q * 8];
#pragma unroll
        for (int ni = 0; ni < 4; ni++) b[ni] = *(const short8*)&Bs[(wn + ni * 16 + r) * 32 + q * 8];
#pragma unroll
        for (int mi = 0; mi < 4; mi++)
#pragma unroll
            for (int ni = 0; ni < 4; ni++)
                acc[mi][ni] = __builtin_amdgcn_mfma_f32_16x16x32_bf16(a[mi], b[ni], acc[mi][ni], 0, 0, 0);
        __syncthreads();
    }

#pragma unroll
    for (int mi = 0; mi < 4; mi++) {
#pragma unroll
        for (int ni = 0; ni < 4; ni++) {
            int gn = n0 + wn + ni * 16 + r;
            float bv = bias ? __bfloat162float(bias[gn]) : 0.f;
#pragma unroll
            for (int reg = 0; reg < 4; reg++) {
                int gm = m0 + wm + mi * 16 + q * 4 + reg;
                if (gm < M) {
                    float val = acc[mi][ni][reg] + bv;
                    if (c32) ((float*)C)[(size_t)gm * N + gn] = val;
                    else     ((bf16*)C)[(size_t)gm * N + gn] = __float2bfloat16(val);
                }
            }
        }
    }

    if constexpr (STATS) {
#pragma unroll
        for (int ni = 0; ni < 4; ni++) {
            float cs = 0.f, cq = 0.f;
#pragma unroll
            for (int mi = 0; mi < 4; mi++)
#pragma unroll
                for (int reg = 0; reg < 4; reg++) {
                    int gm = m0 + wm + mi * 16 + q * 4 + reg;
                    if (gm < M) {
                        float v = acc[mi][ni][reg];
                        cs += v; cq += v * v;
                    }
                }
            int c = wn + ni * 16 + r;
            atomicAdd(&ssum[c], cs);
            atomicAdd(&ssq[c], cq);
        }
        __syncthreads();
        if (tid < 128) {
            float* base = gpart + (size_t)(blockIdx.y & (STRIPES - 1)) * 2 * HDIM;
            atomicAdd(&base[n0 + tid], ssum[tid]);
            atomicAdd(&base[HDIM + n0 + tid], ssq[tid]);
        }
    }
}

// ---------------- CSR aggregation, 128-dim input (fp32 or bf16 x) -----------------
__global__ __launch_bounds__(256) void agg_csr_din(
    const void* __restrict__ x, const int* __restrict__ offsets,
    const int* __restrict__ src, const float* __restrict__ dinv,
    const float* __restrict__ selfw, bf16* __restrict__ out,
    int n, const int* __restrict__ flags)
{
    int wave = threadIdx.x >> 6, lane = threadIdx.x & 63;
    int dst = blockIdx.x * 4 + wave;
    if (dst >= n) return;
    bool f32 = flags[1] != 0;
    int s0 = offsets[dst], s1 = offsets[dst + 1];
    float di = dinv[dst], sw = selfw[dst];
    float a0, a1;
    if (f32) {
        float2 v = ((const float2*)x)[(size_t)dst * 64 + lane];
        a0 = sw * v.x; a1 = sw * v.y;
    } else {
        unsigned u = ((const unsigned*)x)[(size_t)dst * 64 + lane];
        a0 = sw * bf2f((short)(u & 0xFFFF)); a1 = sw * bf2f((short)(u >> 16));
    }
    for (int p = s0; p < s1; p++) {
        int sr = src[p];
        float nm = di * dinv[sr];
        if (f32) {
            float2 v = ((const float2*)x)[(size_t)sr * 64 + lane];
            a0 += nm * v.x; a1 += nm * v.y;
        } else {
            unsigned u = ((const unsigned*)x)[(size_t)sr * 64 + lane];
            a0 += nm * bf2f((short)(u & 0xFFFF)); a1 += nm * bf2f((short)(u >> 16));
        }
    }
    unsigned o = (unsigned)f2bfbits(a0) | ((unsigned)f2bfbits(a1) << 16);
    ((unsigned*)out)[(size_t)dst * 64 + lane] = o;
}

// ---------------- persistent CSR aggregation (512-dim) + fused BN-stats -----------
__global__ __launch_bounds__(256) void agg_csr_stats(
    const bf16* __restrict__ h, const int* __restrict__ offsets,
    const int* __restrict__ src, const float* __restrict__ dinv,
    const float* __restrict__ selfw, bf16* __restrict__ y, int n,
    float* __restrict__ gpart)
{
    __shared__ float red[4][HDIM];
    int t = threadIdx.x;
    int wave = t >> 6, lane = t & 63;
    int f0 = lane * 8;
    int gw = blockIdx.x * 4 + wave;
    int nw = gridDim.x * 4;

    float s8[8] = {0, 0, 0, 0, 0, 0, 0, 0};
    float q8[8] = {0, 0, 0, 0, 0, 0, 0, 0};

    for (int dst = gw; dst < n; dst += nw) {
        int s0 = offsets[dst], s1 = offsets[dst + 1];
        float di = dinv[dst], sw = selfw[dst];
        short8 hv = *(const short8*)(h + (size_t)dst * HDIM + f0);
        float acc[8];
#pragma unroll
        for (int j = 0; j < 8; j++) acc[j] = sw * bf2f(hv[j]);
        for (int p = s0; p < s1; p++) {
            int sr = src[p];
            float nm = di * dinv[sr];
            short8 v = *(const short8*)(h + (size_t)sr * HDIM + f0);
#pragma unroll
            for (int j = 0; j < 8; j++) acc[j] += nm * bf2f(v[j]);
        }
        short8 o;
#pragma unroll
        for (int j = 0; j < 8; j++) {
            ((bf16*)&o)[j] = __float2bfloat16(acc[j]);
            s8[j] += acc[j]; q8[j] += acc[j] * acc[j];
        }
        *(short8*)(y + (size_t)dst * HDIM + f0) = o;
    }

#pragma unroll
    for (int j = 0; j < 8; j++) red[wave][f0 + j] = s8[j];
    __syncthreads();
    float* base = gpart + (size_t)(blockIdx.x & (STRIPES - 1)) * 2 * HDIM;
    if (wave == 0) {
#pragma unroll
        for (int j = 0; j < 8; j++)
            atomicAdd(&base[f0 + j],
                      red[0][f0 + j] + red[1][f0 + j] + red[2][f0 + j] + red[3][f0 + j]);
    }
    __syncthreads();
#pragma unroll
    for (int j = 0; j < 8; j++) red[wave][f0 + j] = q8[j];
    __syncthreads();
    if (wave == 0) {
#pragma unroll
        for (int j = 0; j < 8; j++)
            atomicAdd(&base[HDIM + f0 + j],
                      red[0][f0 + j] + red[1][f0 + j] + red[2][f0 + j] + red[3][f0 + j]);
    }
}

// ---------------- BN coeffs from striped partials ---------------------------------
__global__ void bn_final(const float* __restrict__ gpart,
                         const void* __restrict__ gamma, const void* __restrict__ beta,
                         float* __restrict__ scale, float* __restrict__ shift,
                         float invN, const int* __restrict__ flags)
{
    int f = threadIdx.x;
    float s = 0.f, q = 0.f;
#pragma unroll
    for (int k = 0; k < STRIPES; k++) {
        s += gpart[(size_t)k * 2 * HDIM + f];
        q += gpart[(size_t)k * 2 * HDIM + HDIM + f];
    }
    float g = flags[1] ? ((const float*)gamma)[f]
                       : __bfloat162float(((const bf16*)gamma)[f]);
    float b = flags[1] ? ((const float*)beta)[f]
                       : __bfloat162float(((const bf16*)beta)[f]);
    float mu = s * invN;
    float var = fmaxf(q * invN - mu * mu, 0.f);
    float inv = rsqrtf(var + BN_EPS);
    float sc = g * inv;
    scale[f] = sc;
    shift[f] = b - mu * sc;
}

__global__ __launch_bounds__(256) void bn_apply(
    bf16* __restrict__ y, const float* __restrict__ scale,
    const float* __restrict__ shift, long long total8)
{
    long long idx = (long long)blockIdx.x * 256 + threadIdx.x;
    if (idx >= total8) return;
    int f0 = (int)((idx * 8) & (HDIM - 1));
    short8 v = *(const short8*)((const bf16*)y + idx * 8);
    short8 o;
#pragma unroll
    for (int j = 0; j < 8; j++) {
        float val = scale[f0 + j] * bf2f(v[j]) + shift[f0 + j];
        ((bf16*)&o)[j] = __float2bfloat16(val > 0.f ? val : SLOPE * val);
    }
    *(short8*)(y + idx * 8) = o;
}

// ---------------- pooling with fused BN+LeakyReLU (monotone) ----------------------
__global__ __launch_bounds__(512) void pool_fused(
    const bf16* __restrict__ y, const int* __restrict__ batch,
    const float* __restrict__ scale, const float* __restrict__ shift,
    bf16* __restrict__ pooled, int n)
{
    int g = blockIdx.x;
    int f = threadIdx.x;
    int lo = 0, hi = n;
    while (lo < hi) { int mid = (lo + hi) >> 1; if (batch[mid] < g) lo = mid + 1; else hi = mid; }
    int s = lo;
    hi = n;
    while (lo < hi) { int mid = (lo + hi) >> 1; if (batch[mid] <= g) lo = mid + 1; else hi = mid; }
    int e = lo;
    float mx = -3.0e38f, mn = 3.0e38f;
    for (int rr = s; rr < e; rr++) {
        float v = bf2f(__builtin_bit_cast(short, y[(size_t)rr * HDIM + f]));
        mx = fmaxf(mx, v); mn = fminf(mn, v);
    }
    float outv = 0.f;
    if (s < e) {
        float sc = scale[f];
        float t = sc * (sc >= 0.f ? mx : mn) + shift[f];
        outv = t > 0.f ? t : SLOPE * t;
    }
    pooled[(size_t)g * HDIM + f] = __float2bfloat16(outv);
}

// ---------------- orchestration --------------------------------------------------
extern "C" void kernel_launch(void* const* d_in, const int* in_sizes, int n_in,
                              void* d_out, int out_size, void* d_ws, size_t ws_size,
                              hipStream_t stream)
{
    const void* x     = d_in[0];
    const int*  ei    = (const int*)d_in[1];
    const int*  batch = (const int*)d_in[2];
    // d_in[4]=b1, d_in[8]=b2 cancel in training-mode BatchNorm — unused.

    const int N   = in_sizes[2];
    const int E   = in_sizes[1] / 2;
    const int DIN = 128;
    const int OUT = 256;
    const int G   = out_size / OUT;
    const int Mp  = (N + 127) & ~127;   // row-padded for 128-tile staging

    // workspace carve — ~236 MB
    char* p = (char*)d_ws;
    bf16* B1     = (bf16*)p;  p += (size_t)Mp * HDIM * sizeof(bf16);
    bf16* B2     = (bf16*)p;  p += (size_t)Mp * HDIM * sizeof(bf16);
    bf16* Q      = (bf16*)p;  p += (size_t)Mp * DIN * sizeof(bf16);   // aggx; later pooled[G][512]
    bf16* W1T    = (bf16*)p;  p += (size_t)HDIM * DIN * sizeof(bf16);
    bf16* W2T    = (bf16*)p;  p += (size_t)HDIM * HDIM * sizeof(bf16);
    bf16* WfT    = (bf16*)p;  p += (size_t)OUT * HDIM * sizeof(bf16);
    bf16* bfbf   = (bf16*)p;  p += 512 * sizeof(bf16);
    int* ei32    = (int*)p;   p += (size_t)2 * E * sizeof(int);
    int* batch32 = (int*)p;   p += (size_t)N * sizeof(int);
    float* dinv  = (float*)p; p += (size_t)N * sizeof(float);
    float* selfw = (float*)p; p += (size_t)N * sizeof(float);
    int* offsets = (int*)p;   p += (size_t)(N + 4) * sizeof(int);
    int* cursor  = (int*)p;   p += (size_t)N * sizeof(int);
    int* srcarr  = (int*)p;   p += (size_t)E * sizeof(int);
    int* bsum    = (int*)p;   p += 1024 * sizeof(int);
    float* gpart = (float*)p; p += (size_t)STRIPES * 2 * HDIM * sizeof(float);
    float* sc1   = (float*)p; p += HDIM * sizeof(float);
    float* sh1   = (float*)p; p += HDIM * sizeof(float);
    float* sc2   = (float*)p; p += HDIM * sizeof(float);
    float* sh2   = (float*)p; p += HDIM * sizeof(float);
    int* flags   = (int*)p;   p += 4 * sizeof(int);

    // ---- dtype detection + canonicalization ----
    detect_types<<<1, 256, 0, stream>>>(ei, (const unsigned*)x, flags);
    conv_idx<<<(2 * E + 255) / 256, 256, 0, stream>>>(ei, ei32, 2 * E, flags);
    conv_idx<<<(N + 255) / 256, 256, 0, stream>>>(batch, batch32, N, flags);
    wt_conv<<<(DIN * HDIM + 255) / 256, 256, 0, stream>>>(d_in[3], W1T, DIN, HDIM, flags);
    wt_conv<<<(HDIM * HDIM + 255) / 256, 256, 0, stream>>>(d_in[7], W2T, HDIM, HDIM, flags);
    wt_conv<<<(HDIM * OUT + 255) / 256, 256, 0, stream>>>(d_in[11], WfT, HDIM, OUT, flags);
    conv_float<<<1, 256, 0, stream>>>(d_in[12], bfbf, OUT, flags);

    const int* rows = ei32;
    const int* cols = ei32 + E;

    // ---- CSR + degrees (shared by both conv layers) ----
    hipMemsetAsync(cursor, 0, (size_t)N * sizeof(int), stream);
    count_deg<<<(E + 255) / 256, 256, 0, stream>>>(cols, cursor, E);
    finalize_deg<<<(N + 255) / 256, 256, 0, stream>>>(cursor, dinv, selfw, N);
    int nb = (N + 511) / 512;
    scan_part<<<nb, 256, 0, stream>>>(cursor, offsets, bsum, N);
    scan_tops<<<1, 1024, 0, stream>>>(bsum, nb);
    scan_add<<<nb, 256, 0, stream>>>(offsets, bsum, N, E);
    hipMemsetAsync(cursor, 0, (size_t)N * sizeof(int), stream);
    scatter_edges<<<(E + 255) / 256, 256, 0, stream>>>(rows, cols, offsets, cursor, srcarr, E);

    long long tot8 = (long long)N * HDIM / 8;
    dim3 g1(HDIM / 128, Mp / 128);
    size_t gpart_bytes = (size_t)STRIPES * 2 * HDIM * sizeof(float);

    // ---- layer 1: aggregate x (agg is linear), GEMM w/ fused stats ----
    agg_csr_din<<<(N + 3) / 4, 256, 0, stream>>>(x, offsets, srcarr, dinv, selfw, Q, N, flags);
    hipMemsetAsync(gpart, 0, gpart_bytes, stream);
    gemm_m97<true><<<g1, 256, 0, stream>>>(Q, W1T, B2, nullptr, N, DIN, HDIM, nullptr, gpart);
    bn_final<<<1, HDIM, 0, stream>>>(gpart, d_in[5], d_in[6], sc1, sh1, 1.0f / N, flags);
    bn_apply<<<(int)((tot8 + 255) / 256), 256, 0, stream>>>(B2, sc1, sh1, tot8);

    // ---- layer 2: GEMM, persistent aggregate w/ fused stats ----
    gemm_m97<false><<<g1, 256, 0, stream>>>(B2, W2T, B1, nullptr, N, HDIM, HDIM, nullptr, nullptr);
    hipMemsetAsync(gpart, 0, gpart_bytes, stream);
    agg_csr_stats<<<2048, 256, 0, stream>>>(B1, offsets, srcarr, dinv, selfw, B2, N, gpart);
    bn_final<<<1, HDIM, 0, stream>>>(gpart, d_in[9], d_in[10], sc2, sh2, 1.0f / N, flags);

    // ---- pool (fused BN+leaky, monotone) + head GEMM ----
    pool_fused<<<G, HDIM, 0, stream>>>(B2, batch32, sc2, sh2, Q, N);
    gemm_m97<false><<<dim3(OUT / 128, G / 128), 256, 0, stream>>>(
        Q, WfT, d_out, bfbf, G, HDIM, OUT, flags + 1, nullptr);
}